// Round 1
// baseline (780.115 us; speedup 1.0000x reference)
//
#include <hip/hip_runtime.h>

typedef __attribute__((ext_vector_type(8))) short short8;
typedef __attribute__((ext_vector_type(4))) float f32x4;

#define B_SZ 8192
#define H_SZ 1024
#define R_SZ 16

__device__ __forceinline__ unsigned short f2bf(float f) {
  union { float f; unsigned u; } v; v.f = f;
  unsigned u = v.u + 0x7FFFu + ((v.u >> 16) & 1u);
  return (unsigned short)(u >> 16);
}

// ---------------- x -> bf16 ----------------
__global__ __launch_bounds__(256) void cvt_bf16(const float* __restrict__ s,
                                                unsigned short* __restrict__ d) {
  size_t i = ((size_t)blockIdx.x * 256 + threadIdx.x) * 8;
  float4 f0 = *(const float4*)(s + i);
  float4 f1 = *(const float4*)(s + i + 4);
  short8 v;
  v[0] = (short)f2bf(f0.x); v[1] = (short)f2bf(f0.y);
  v[2] = (short)f2bf(f0.z); v[3] = (short)f2bf(f0.w);
  v[4] = (short)f2bf(f1.x); v[5] = (short)f2bf(f1.y);
  v[6] = (short)f2bf(f1.z); v[7] = (short)f2bf(f1.w);
  *(short8*)(d + i) = v;
}

// ------------- transpose + convert: src[rows][cols] f32 -> dst[cols][rows] bf16 -------------
__global__ __launch_bounds__(256) void transpose_cvt(const float* __restrict__ src,
                                                     unsigned short* __restrict__ dst,
                                                     int rows, int cols) {
  __shared__ float t[32][33];
  size_t zoff = (size_t)blockIdx.z * (size_t)rows * cols;
  int c0 = blockIdx.x * 32, r0 = blockIdx.y * 32;
  int tx = threadIdx.x, ty = threadIdx.y;
#pragma unroll
  for (int i = 0; i < 4; ++i)
    t[ty + 8 * i][tx] = src[zoff + (size_t)(r0 + ty + 8 * i) * cols + c0 + tx];
  __syncthreads();
#pragma unroll
  for (int i = 0; i < 4; ++i)
    dst[zoff + (size_t)(c0 + ty + 8 * i) * rows + r0 + tx] = f2bf(t[tx][ty + 8 * i]);
}

// ------------- gate: softmax(x@Wa+ba) * sigmoid(x@Wc+bc), renormalized -------------
__global__ __launch_bounds__(64) void gate_kernel(const float* __restrict__ x,
                                                  const float* __restrict__ Wa,
                                                  const float* __restrict__ ba,
                                                  const float* __restrict__ Wc,
                                                  const float* __restrict__ bc,
                                                  float* __restrict__ comb,
                                                  float* __restrict__ conf) {
  int b = blockIdx.x, l = threadIdx.x;
  const float* xr = x + (size_t)b * H_SZ;
  float xv[16];
#pragma unroll
  for (int j = 0; j < 16; ++j) xv[j] = xr[l + 64 * j];
  float la[16], lcf[16];
#pragma unroll
  for (int r = 0; r < 16; ++r) {
    float sa = 0.f, sc = 0.f;
#pragma unroll
    for (int j = 0; j < 16; ++j) {
      int h = l + 64 * j;
      sa += xv[j] * Wa[h * 16 + r];
      sc += xv[j] * Wc[r * H_SZ + h];
    }
#pragma unroll
    for (int off = 32; off > 0; off >>= 1) {
      sa += __shfl_xor(sa, off);
      sc += __shfl_xor(sc, off);
    }
    la[r] = sa + ba[r];
    lcf[r] = sc + bc[r];
  }
  float mx = la[0];
#pragma unroll
  for (int r = 1; r < 16; ++r) mx = fmaxf(mx, la[r]);
  float se = 0.f;
#pragma unroll
  for (int r = 0; r < 16; ++r) { la[r] = expf(la[r] - mx); se += la[r]; }
  float cb[16]; float cs = 0.f;
#pragma unroll
  for (int r = 0; r < 16; ++r) {
    float cf = 1.f / (1.f + expf(-lcf[r]));
    lcf[r] = cf;
    cb[r] = (la[r] / se) * cf;
    cs += cb[r];
  }
  float inv = 1.f / (cs + 1e-8f);
  if (l < 16) {
    float cv = 0.f, qv = 0.f;
#pragma unroll
    for (int r = 0; r < 16; ++r)
      if (r == l) { cv = lcf[r]; qv = cb[r] * inv; }
    conf[b * 16 + l] = cv;
    comb[b * 16 + l] = qv;
  }
}

// ------------- NT bf16 GEMM, 128x128 tile, BK=64, 4 waves -------------
// MODE 0: Hp[m,n] = bf16( relu(acc + b1[r,d]) * comb[m,r] ),  r = r_base + n/1024
// MODE 1: Out[m,n] (+)= acc (+ sum_r comb[m,r]*b2[r,n] when !accum)
template <int MODE>
__global__ __launch_bounds__(256) void gemm_nt(
    const unsigned short* __restrict__ A, int lda,
    const unsigned short* __restrict__ B, int ldb, int K,
    unsigned short* __restrict__ Hp, int ldh,
    const float* __restrict__ b1v,
    float* __restrict__ Out,
    const float* __restrict__ b2v,
    const float* __restrict__ comb,
    int r_base, int accum) {
  __shared__ short smem[16384];  // A tile [128][64] bf16 (16KB) + B tile (16KB)
  short* As = smem;
  short* Bs = smem + 8192;

  const int tid = threadIdx.x;
  const int lane = tid & 63;
  const int wid = tid >> 6;
  const int wm = wid >> 1, wn = wid & 1;
  const int lr = lane >> 4, lc = lane & 15;

  const int bn0 = blockIdx.x * 128;
  const int bm0 = blockIdx.y * 128;

  int srow[4], ssc[4];
#pragma unroll
  for (int i = 0; i < 4; ++i) {
    int idx = i * 256 + tid;
    srow[i] = idx >> 3;   // tile row 0..127
    ssc[i] = idx & 7;     // 16B chunk within 128B row
  }

  const f32x4 zero = {0.f, 0.f, 0.f, 0.f};
  f32x4 acc[4][4];
#pragma unroll
  for (int i = 0; i < 4; ++i)
#pragma unroll
    for (int j = 0; j < 4; ++j) acc[i][j] = zero;

  const int KT = K >> 6;

  short8 va[4], vb[4];
#pragma unroll
  for (int i = 0; i < 4; ++i) {
    va[i] = *(const short8*)(A + (size_t)(bm0 + srow[i]) * lda + ssc[i] * 8);
    vb[i] = *(const short8*)(B + (size_t)(bn0 + srow[i]) * ldb + ssc[i] * 8);
  }

  for (int kt = 0; kt < KT; ++kt) {
    __syncthreads();  // previous tile's reads complete
#pragma unroll
    for (int i = 0; i < 4; ++i) {
      // XOR-swizzle: logical chunk c stored at slot c^(row&7)  (bank-conflict-free reads)
      *(short8*)(As + srow[i] * 64 + ((ssc[i] ^ (srow[i] & 7)) * 8)) = va[i];
      *(short8*)(Bs + srow[i] * 64 + ((ssc[i] ^ (srow[i] & 7)) * 8)) = vb[i];
    }
    __syncthreads();
    if (kt + 1 < KT) {  // prefetch next tile into regs; hides under MFMA below
      int k0 = (kt + 1) << 6;
#pragma unroll
      for (int i = 0; i < 4; ++i) {
        va[i] = *(const short8*)(A + (size_t)(bm0 + srow[i]) * lda + k0 + ssc[i] * 8);
        vb[i] = *(const short8*)(B + (size_t)(bn0 + srow[i]) * ldb + k0 + ssc[i] * 8);
      }
    }
#pragma unroll
    for (int c = 0; c < 2; ++c) {
      short8 af[4], bfr[4];
#pragma unroll
      for (int f = 0; f < 4; ++f) {
        int ra = wm * 64 + f * 16 + lc;
        af[f] = *(const short8*)(As + ra * 64 + (((c * 4 + lr) ^ (ra & 7)) * 8));
        int rb = wn * 64 + f * 16 + lc;
        bfr[f] = *(const short8*)(Bs + rb * 64 + (((c * 4 + lr) ^ (rb & 7)) * 8));
      }
#pragma unroll
      for (int mf = 0; mf < 4; ++mf)
#pragma unroll
        for (int nf = 0; nf < 4; ++nf)
          acc[mf][nf] = __builtin_amdgcn_mfma_f32_16x16x32_bf16(af[mf], bfr[nf],
                                                                acc[mf][nf], 0, 0, 0);
    }
  }

  // epilogue: C/D layout col=lane&15, row=(lane>>4)*4+reg
#pragma unroll
  for (int mf = 0; mf < 4; ++mf) {
#pragma unroll
    for (int nf = 0; nf < 4; ++nf) {
      int m0 = bm0 + wm * 64 + mf * 16 + lr * 4;
      int n = bn0 + wn * 64 + nf * 16 + lc;
      f32x4 a = acc[mf][nf];
      if (MODE == 0) {
        int r = r_base + (n >> 10);
        int d = n & 1023;
        float bias = b1v[r * H_SZ + d];
#pragma unroll
        for (int j = 0; j < 4; ++j) {
          float v = fmaxf(a[j] + bias, 0.f) * comb[(size_t)(m0 + j) * 16 + r];
          Hp[(size_t)(m0 + j) * ldh + n] = f2bf(v);
        }
      } else {
#pragma unroll
        for (int j = 0; j < 4; ++j) {
          size_t row = (size_t)(m0 + j);
          float v = a[j];
          if (accum) {
            v += Out[row * H_SZ + n];
          } else {
            float bs = 0.f;
#pragma unroll
            for (int r = 0; r < 16; ++r)
              bs += comb[row * 16 + r] * b2v[r * H_SZ + n];
            v += bs;
          }
          Out[row * H_SZ + n] = v;
        }
      }
    }
  }
}

extern "C" void kernel_launch(void* const* d_in, const int* in_sizes, int n_in,
                              void* d_out, int out_size, void* d_ws, size_t ws_size,
                              hipStream_t stream) {
  if (n_in < 9) return;
  const float* x  = (const float*)d_in[0];
  const float* Wa = (const float*)d_in[1];
  const float* ba = (const float*)d_in[2];
  const float* W1 = (const float*)d_in[3];
  const float* b1 = (const float*)d_in[4];
  const float* W2 = (const float*)d_in[5];
  const float* b2 = (const float*)d_in[6];
  const float* Wc = (const float*)d_in[7];
  const float* bc = (const float*)d_in[8];

  float* out = (float*)d_out;
  float* conf = out + (size_t)B_SZ * H_SZ;

  char* w = (char*)d_ws;
  unsigned short* xb = (unsigned short*)w;  w += (size_t)B_SZ * H_SZ * 2;
  unsigned short* W1T = (unsigned short*)w; w += (size_t)R_SZ * H_SZ * H_SZ * 2;
  unsigned short* W2T = (unsigned short*)w; w += (size_t)R_SZ * H_SZ * H_SZ * 2;
  float* comb = (float*)w;                  w += (size_t)B_SZ * R_SZ * 4;
  unsigned short* Hp = (unsigned short*)w;
  size_t used = (size_t)(w - (char*)d_ws);

  // pick largest rule-group size G whose Hp buffer fits in remaining ws
  int G = 16;
  while (G > 1 && used + (size_t)B_SZ * G * H_SZ * 2 > ws_size) G >>= 1;
  if (used + (size_t)B_SZ * G * H_SZ * 2 > ws_size) return;  // ws too small

  cvt_bf16<<<dim3((B_SZ * H_SZ) / (256 * 8)), dim3(256), 0, stream>>>(x, xb);
  dim3 tb(32, 8);
  transpose_cvt<<<dim3(32, 32, 16), tb, 0, stream>>>(W1, W1T, H_SZ, H_SZ);        // per-rule [h,d]->[d,h]
  transpose_cvt<<<dim3(32, 512, 1), tb, 0, stream>>>(W2, W2T, R_SZ * H_SZ, H_SZ); // [(r,d),o]->[o,(r,d)]
  gate_kernel<<<dim3(B_SZ), dim3(64), 0, stream>>>(x, Wa, ba, Wc, bc, comb, conf);

  int ngroups = R_SZ / G;
  for (int g = 0; g < ngroups; ++g) {
    // Hp[b, (r_local,d)] = comb[b,r] * relu(x @ W1[r] + b1[r])   for r in group g
    gemm_nt<0><<<dim3(G * 8, 64), dim3(256), 0, stream>>>(
        xb, H_SZ,
        W1T + (size_t)g * G * H_SZ * H_SZ, H_SZ, H_SZ,
        Hp, G * H_SZ, b1, nullptr, nullptr, comb, g * G, 0);
    // out[b,o] (+)= Hp @ W2[group rows]  (+ gate-weighted b2 on first group)
    gemm_nt<1><<<dim3(8, 64), dim3(256), 0, stream>>>(
        Hp, G * H_SZ,
        W2T + (size_t)g * G * H_SZ, R_SZ * H_SZ, G * H_SZ,
        nullptr, 0, nullptr, out, b2, comb, 0, (g > 0) ? 1 : 0);
  }
}

// Round 2
// 761.460 us; speedup vs baseline: 1.0245x; 1.0245x over previous
//
#include <hip/hip_runtime.h>

typedef __attribute__((ext_vector_type(8))) short short8;
typedef __attribute__((ext_vector_type(4))) float f32x4;

#define B_SZ 8192
#define H_SZ 1024
#define R_SZ 16

__device__ __forceinline__ unsigned short f2bf(float f) {
  union { float f; unsigned u; } v; v.f = f;
  unsigned u = v.u + 0x7FFFu + ((v.u >> 16) & 1u);
  return (unsigned short)(u >> 16);
}

// ---------------- x -> bf16 ----------------
__global__ __launch_bounds__(256) void cvt_bf16(const float* __restrict__ s,
                                                unsigned short* __restrict__ d) {
  size_t i = ((size_t)blockIdx.x * 256 + threadIdx.x) * 8;
  float4 f0 = *(const float4*)(s + i);
  float4 f1 = *(const float4*)(s + i + 4);
  short8 v;
  v[0] = (short)f2bf(f0.x); v[1] = (short)f2bf(f0.y);
  v[2] = (short)f2bf(f0.z); v[3] = (short)f2bf(f0.w);
  v[4] = (short)f2bf(f1.x); v[5] = (short)f2bf(f1.y);
  v[6] = (short)f2bf(f1.z); v[7] = (short)f2bf(f1.w);
  *(short8*)(d + i) = v;
}

// ------------- transpose + convert: src[rows][cols] f32 -> dst[cols][rows] bf16 -------------
__global__ __launch_bounds__(256) void transpose_cvt(const float* __restrict__ src,
                                                     unsigned short* __restrict__ dst,
                                                     int rows, int cols) {
  __shared__ float t[32][33];
  size_t zoff = (size_t)blockIdx.z * (size_t)rows * cols;
  int c0 = blockIdx.x * 32, r0 = blockIdx.y * 32;
  int tx = threadIdx.x, ty = threadIdx.y;
#pragma unroll
  for (int i = 0; i < 4; ++i)
    t[ty + 8 * i][tx] = src[zoff + (size_t)(r0 + ty + 8 * i) * cols + c0 + tx];
  __syncthreads();
#pragma unroll
  for (int i = 0; i < 4; ++i)
    dst[zoff + (size_t)(c0 + ty + 8 * i) * rows + r0 + tx] = f2bf(t[tx][ty + 8 * i]);
}

// ------------- Wa [1024][16] f32 -> WaT [16][1024] f32 (so gate reads are coalesced) -------------
__global__ __launch_bounds__(256) void transpose_wa(const float* __restrict__ Wa,
                                                    float* __restrict__ WaT) {
  int t = blockIdx.x * 256 + threadIdx.x;  // 16384 total
  int h = t >> 4, r = t & 15;
  WaT[r * H_SZ + h] = Wa[t];
}

// ------------- gate: softmax(x@Wa+ba) * sigmoid(x@Wc+bc), renormalized -------------
// one wave per row; all weight reads coalesced (row-major WaT / Wc)
__global__ __launch_bounds__(256) void gate_kernel(const float* __restrict__ x,
                                                   const float* __restrict__ WaT,
                                                   const float* __restrict__ ba,
                                                   const float* __restrict__ Wc,
                                                   const float* __restrict__ bc,
                                                   float* __restrict__ comb,
                                                   float* __restrict__ conf) {
  int b = blockIdx.x * 4 + (threadIdx.x >> 6);
  int l = threadIdx.x & 63;
  const float* xr = x + (size_t)b * H_SZ;
  float xv[16];
#pragma unroll
  for (int j = 0; j < 16; ++j) xv[j] = xr[l + 64 * j];
  float la[16], lcf[16];
#pragma unroll
  for (int r = 0; r < 16; ++r) {
    float sa = 0.f, sc = 0.f;
#pragma unroll
    for (int j = 0; j < 16; ++j) {
      int h = l + 64 * j;
      sa += xv[j] * WaT[r * H_SZ + h];
      sc += xv[j] * Wc[r * H_SZ + h];
    }
#pragma unroll
    for (int off = 32; off > 0; off >>= 1) {
      sa += __shfl_xor(sa, off);
      sc += __shfl_xor(sc, off);
    }
    la[r] = sa + ba[r];
    lcf[r] = sc + bc[r];
  }
  float mx = la[0];
#pragma unroll
  for (int r = 1; r < 16; ++r) mx = fmaxf(mx, la[r]);
  float se = 0.f;
#pragma unroll
  for (int r = 0; r < 16; ++r) { la[r] = expf(la[r] - mx); se += la[r]; }
  float cb[16]; float cs = 0.f;
#pragma unroll
  for (int r = 0; r < 16; ++r) {
    float cf = 1.f / (1.f + expf(-lcf[r]));
    lcf[r] = cf;
    cb[r] = (la[r] / se) * cf;
    cs += cb[r];
  }
  float inv = 1.f / (cs + 1e-8f);
  if (l < 16) {
    float cv = 0.f, qv = 0.f;
#pragma unroll
    for (int r = 0; r < 16; ++r)
      if (r == l) { cv = lcf[r]; qv = cb[r] * inv; }
    conf[b * 16 + l] = cv;
    comb[b * 16 + l] = qv;
  }
}

// async global->LDS, 16B per lane; LDS dest is wave-uniform base + lane*16
__device__ __forceinline__ void gload16(const unsigned short* g, unsigned short* l) {
  __builtin_amdgcn_global_load_lds(
      (const __attribute__((address_space(1))) unsigned int*)g,
      (__attribute__((address_space(3))) unsigned int*)l, 16, 0, 0);
}

// ------------- NT bf16 GEMM, 128x128 tile, BK=64, 4 waves, dbuf + global_load_lds -------------
// MODE 0: Hp[m,n] = bf16( relu(acc + b1[r,d]) * comb[m,r] ),  r = r_base + n/1024
// MODE 1: Out[m,n] (+)= acc (+ sum_r comb[m,r]*b2[r,n] when !accum)
template <int MODE>
__global__ __launch_bounds__(256) void gemm_nt(
    const unsigned short* __restrict__ A, int lda,
    const unsigned short* __restrict__ B, int ldb, int K,
    unsigned short* __restrict__ Hp, int ldh,
    const float* __restrict__ b1v,
    float* __restrict__ Out,
    const float* __restrict__ b2v,
    const float* __restrict__ comb,
    int r_base, int accum) {
  __shared__ short smem[32768];  // 64KB: 2 x (A[128][64] 16KB + B[128][64] 16KB)

  const int tid = threadIdx.x;
  const int lane = tid & 63;
  const int wid = tid >> 6;
  const int wm = wid >> 1, wn = wid & 1;
  const int lr = lane >> 4, lc = lane & 15;

  const int bn0 = blockIdx.x * 128;
  const int bm0 = blockIdx.y * 128;

  // staging decomposition: idx = i*256+tid covers 128 rows x 8 chunks of 16B
  int srow[4], schk[4], ubase[4];
#pragma unroll
  for (int i = 0; i < 4; ++i) {
    int idx = i * 256 + tid;
    srow[i] = idx >> 3;                       // tile row 0..127
    schk[i] = (idx & 7) ^ (srow[i] & 7);      // swizzled SOURCE chunk (involution)
    ubase[i] = (i * 256 + (tid & 192)) * 8;   // wave-uniform LDS elem base
  }

  const f32x4 zero = {0.f, 0.f, 0.f, 0.f};
  f32x4 acc[4][4];
#pragma unroll
  for (int i = 0; i < 4; ++i)
#pragma unroll
    for (int j = 0; j < 4; ++j) acc[i][j] = zero;

  const int KT = K >> 6;

  auto stage = [&](int bf, int kt) {
    const int k0 = kt << 6;
    short* lb = smem + bf * 16384;
#pragma unroll
    for (int i = 0; i < 4; ++i) {
      gload16((const unsigned short*)A + (size_t)(bm0 + srow[i]) * lda + k0 + schk[i] * 8,
              (unsigned short*)(lb + ubase[i]));
      gload16((const unsigned short*)B + (size_t)(bn0 + srow[i]) * ldb + k0 + schk[i] * 8,
              (unsigned short*)(lb + 8192 + ubase[i]));
    }
  };

  stage(0, 0);
  __syncthreads();  // drains vmcnt(0): buf0 ready

  for (int kt = 0; kt < KT; ++kt) {
    const int cur = kt & 1;
    if (kt + 1 < KT) stage(cur ^ 1, kt + 1);  // async loads in flight during MFMA
    const short* As = smem + cur * 16384;
    const short* Bs = As + 8192;
#pragma unroll
    for (int c = 0; c < 2; ++c) {
      short8 af[4], bfr[4];
#pragma unroll
      for (int f = 0; f < 4; ++f) {
        int ra = wm * 64 + f * 16 + lc;
        af[f] = *(const short8*)(As + ra * 64 + (((c * 4 + lr) ^ (ra & 7)) * 8));
        int rb = wn * 64 + f * 16 + lc;
        bfr[f] = *(const short8*)(Bs + rb * 64 + (((c * 4 + lr) ^ (rb & 7)) * 8));
      }
#pragma unroll
      for (int mf = 0; mf < 4; ++mf)
#pragma unroll
        for (int nf = 0; nf < 4; ++nf)
          acc[mf][nf] = __builtin_amdgcn_mfma_f32_16x16x32_bf16(af[mf], bfr[nf],
                                                                acc[mf][nf], 0, 0, 0);
    }
    __syncthreads();  // all waves done reading cur; next buf's loads drained (vmcnt 0)
  }

  // epilogue: C/D layout col=lane&15, row=(lane>>4)*4+reg
#pragma unroll
  for (int mf = 0; mf < 4; ++mf) {
#pragma unroll
    for (int nf = 0; nf < 4; ++nf) {
      int m0 = bm0 + wm * 64 + mf * 16 + lr * 4;
      int n = bn0 + wn * 64 + nf * 16 + lc;
      f32x4 a = acc[mf][nf];
      if (MODE == 0) {
        int r = r_base + (n >> 10);
        int d = n & 1023;
        float bias = b1v[r * H_SZ + d];
#pragma unroll
        for (int j = 0; j < 4; ++j) {
          float v = fmaxf(a[j] + bias, 0.f) * comb[(size_t)(m0 + j) * 16 + r];
          Hp[(size_t)(m0 + j) * ldh + n] = f2bf(v);
        }
      } else {
#pragma unroll
        for (int j = 0; j < 4; ++j) {
          size_t row = (size_t)(m0 + j);
          float v = a[j];
          if (accum) {
            v += Out[row * H_SZ + n];
          } else {
            float bs = 0.f;
#pragma unroll
            for (int r = 0; r < 16; ++r)
              bs += comb[row * 16 + r] * b2v[r * H_SZ + n];
            v += bs;
          }
          Out[row * H_SZ + n] = v;
        }
      }
    }
  }
}

extern "C" void kernel_launch(void* const* d_in, const int* in_sizes, int n_in,
                              void* d_out, int out_size, void* d_ws, size_t ws_size,
                              hipStream_t stream) {
  if (n_in < 9) return;
  const float* x  = (const float*)d_in[0];
  const float* Wa = (const float*)d_in[1];
  const float* ba = (const float*)d_in[2];
  const float* W1 = (const float*)d_in[3];
  const float* b1 = (const float*)d_in[4];
  const float* W2 = (const float*)d_in[5];
  const float* b2 = (const float*)d_in[6];
  const float* Wc = (const float*)d_in[7];
  const float* bc = (const float*)d_in[8];

  float* out = (float*)d_out;
  float* conf = out + (size_t)B_SZ * H_SZ;

  char* w = (char*)d_ws;
  unsigned short* xb = (unsigned short*)w;  w += (size_t)B_SZ * H_SZ * 2;
  unsigned short* W1T = (unsigned short*)w; w += (size_t)R_SZ * H_SZ * H_SZ * 2;
  unsigned short* W2T = (unsigned short*)w; w += (size_t)R_SZ * H_SZ * H_SZ * 2;
  float* comb = (float*)w;                  w += (size_t)B_SZ * R_SZ * 4;
  float* WaT = (float*)w;                   w += (size_t)R_SZ * H_SZ * 4;
  unsigned short* Hp = (unsigned short*)w;
  size_t used = (size_t)(w - (char*)d_ws);

  // pick largest rule-group size G whose Hp buffer fits in remaining ws
  int G = 16;
  while (G > 1 && used + (size_t)B_SZ * G * H_SZ * 2 > ws_size) G >>= 1;
  if (used + (size_t)B_SZ * G * H_SZ * 2 > ws_size) return;  // ws too small

  cvt_bf16<<<dim3((B_SZ * H_SZ) / (256 * 8)), dim3(256), 0, stream>>>(x, xb);
  dim3 tb(32, 8);
  transpose_cvt<<<dim3(32, 32, 16), tb, 0, stream>>>(W1, W1T, H_SZ, H_SZ);        // per-rule [h,d]->[d,h]
  transpose_cvt<<<dim3(32, 512, 1), tb, 0, stream>>>(W2, W2T, R_SZ * H_SZ, H_SZ); // [(r,d),o]->[o,(r,d)]
  transpose_wa<<<dim3(64), dim3(256), 0, stream>>>(Wa, WaT);
  gate_kernel<<<dim3(B_SZ / 4), dim3(256), 0, stream>>>(x, WaT, ba, Wc, bc, comb, conf);

  int ngroups = R_SZ / G;
  for (int g = 0; g < ngroups; ++g) {
    // Hp[b, (r_local,d)] = comb[b,r] * relu(x @ W1[r] + b1[r])   for r in group g
    gemm_nt<0><<<dim3(G * 8, 64), dim3(256), 0, stream>>>(
        xb, H_SZ,
        W1T + (size_t)g * G * H_SZ * H_SZ, H_SZ, H_SZ,
        Hp, G * H_SZ, b1, nullptr, nullptr, comb, g * G, 0);
    // out[b,o] (+)= Hp @ W2[group rows]  (+ gate-weighted b2 on first group)
    gemm_nt<1><<<dim3(8, 64), dim3(256), 0, stream>>>(
        Hp, G * H_SZ,
        W2T + (size_t)g * G * H_SZ, R_SZ * H_SZ, G * H_SZ,
        nullptr, 0, nullptr, out, b2, comb, 0, (g > 0) ? 1 : 0);
  }
}

// Round 3
// 758.760 us; speedup vs baseline: 1.0281x; 1.0036x over previous
//
#include <hip/hip_runtime.h>

typedef __attribute__((ext_vector_type(8))) short short8;
typedef __attribute__((ext_vector_type(4))) float f32x4;

#define B_SZ 8192
#define H_SZ 1024
#define R_SZ 16

__device__ __forceinline__ unsigned short f2bf(float f) {
  union { float f; unsigned u; } v; v.f = f;
  unsigned u = v.u + 0x7FFFu + ((v.u >> 16) & 1u);
  return (unsigned short)(u >> 16);
}

// ------------- transpose + convert: src[rows][cols] f32 -> dst[cols][rows] bf16 -------------
__global__ __launch_bounds__(256) void transpose_cvt(const float* __restrict__ src,
                                                     unsigned short* __restrict__ dst,
                                                     int rows, int cols) {
  __shared__ float t[32][33];
  size_t zoff = (size_t)blockIdx.z * (size_t)rows * cols;
  int c0 = blockIdx.x * 32, r0 = blockIdx.y * 32;
  int tx = threadIdx.x, ty = threadIdx.y;
#pragma unroll
  for (int i = 0; i < 4; ++i)
    t[ty + 8 * i][tx] = src[zoff + (size_t)(r0 + ty + 8 * i) * cols + c0 + tx];
  __syncthreads();
#pragma unroll
  for (int i = 0; i < 4; ++i)
    dst[zoff + (size_t)(c0 + ty + 8 * i) * rows + r0 + tx] = f2bf(t[tx][ty + 8 * i]);
}

// ------------- Wa [1024][16] f32 -> WaT [16][1024] f32 (coalesced gate reads) -------------
__global__ __launch_bounds__(256) void transpose_wa(const float* __restrict__ Wa,
                                                    float* __restrict__ WaT) {
  int t = blockIdx.x * 256 + threadIdx.x;  // 16384 total
  int h = t >> 4, r = t & 15;
  WaT[r * H_SZ + h] = Wa[t];
}

// ------------- gate: softmax(x@Wa+ba) * sigmoid(x@Wc+bc), renormalized; also emits xb=bf16(x) -------------
// one wave per row; all weight reads coalesced (row-major WaT / Wc)
__global__ __launch_bounds__(256) void gate_kernel(const float* __restrict__ x,
                                                   const float* __restrict__ WaT,
                                                   const float* __restrict__ ba,
                                                   const float* __restrict__ Wc,
                                                   const float* __restrict__ bc,
                                                   float* __restrict__ comb,
                                                   float* __restrict__ conf,
                                                   unsigned short* __restrict__ xb) {
  int b = blockIdx.x * 4 + (threadIdx.x >> 6);
  int l = threadIdx.x & 63;
  const float* xr = x + (size_t)b * H_SZ;
  unsigned short* xbr = xb + (size_t)b * H_SZ;
  float xv[16];
#pragma unroll
  for (int j = 0; j < 16; ++j) xv[j] = xr[l + 64 * j];
#pragma unroll
  for (int j = 0; j < 16; ++j) xbr[l + 64 * j] = f2bf(xv[j]);  // coalesced per j
  float la[16], lcf[16];
#pragma unroll
  for (int r = 0; r < 16; ++r) {
    float sa = 0.f, sc = 0.f;
#pragma unroll
    for (int j = 0; j < 16; ++j) {
      int h = l + 64 * j;
      sa += xv[j] * WaT[r * H_SZ + h];
      sc += xv[j] * Wc[r * H_SZ + h];
    }
#pragma unroll
    for (int off = 32; off > 0; off >>= 1) {
      sa += __shfl_xor(sa, off);
      sc += __shfl_xor(sc, off);
    }
    la[r] = sa + ba[r];
    lcf[r] = sc + bc[r];
  }
  float mx = la[0];
#pragma unroll
  for (int r = 1; r < 16; ++r) mx = fmaxf(mx, la[r]);
  float se = 0.f;
#pragma unroll
  for (int r = 0; r < 16; ++r) { la[r] = expf(la[r] - mx); se += la[r]; }
  float cb[16]; float cs = 0.f;
#pragma unroll
  for (int r = 0; r < 16; ++r) {
    float cf = 1.f / (1.f + expf(-lcf[r]));
    lcf[r] = cf;
    cb[r] = (la[r] / se) * cf;
    cs += cb[r];
  }
  float inv = 1.f / (cs + 1e-8f);
  if (l < 16) {
    float cv = 0.f, qv = 0.f;
#pragma unroll
    for (int r = 0; r < 16; ++r)
      if (r == l) { cv = lcf[r]; qv = cb[r] * inv; }
    conf[b * 16 + l] = cv;
    comb[b * 16 + l] = qv;
  }
}

// ------------- NT bf16 GEMM, 128x128 tile, BK=64, 4 waves, 32KB LDS, reg prefetch -------------
// MODE 0: Hp[m,n] = bf16( relu(acc + b1[r,d]) * comb[m,r] ),  r = r_base + n/1024
// MODE 1: Out[m,n] (+)= acc (+ sum_r comb[m,r]*b2[r,n] when !accum)
template <int MODE>
__global__ __launch_bounds__(256) void gemm_nt(
    const unsigned short* __restrict__ A, int lda,
    const unsigned short* __restrict__ B, int ldb, int K,
    unsigned short* __restrict__ Hp, int ldh,
    const float* __restrict__ b1v,
    float* __restrict__ Out,
    const float* __restrict__ b2v,
    const float* __restrict__ comb,
    int r_base, int accum) {
  __shared__ short smem[16384];  // A tile [128][64] bf16 (16KB) + B tile (16KB)
  short* As = smem;
  short* Bs = smem + 8192;

  const int tid = threadIdx.x;
  const int lane = tid & 63;
  const int wid = tid >> 6;
  const int wm = wid >> 1, wn = wid & 1;
  const int lr = lane >> 4, lc = lane & 15;

  const int bn0 = blockIdx.x * 128;
  const int bm0 = blockIdx.y * 128;

  int srow[4], ssc[4];
#pragma unroll
  for (int i = 0; i < 4; ++i) {
    int idx = i * 256 + tid;
    srow[i] = idx >> 3;   // tile row 0..127
    ssc[i] = idx & 7;     // 16B chunk within 128B row
  }

  const f32x4 zero = {0.f, 0.f, 0.f, 0.f};
  f32x4 acc[4][4];
#pragma unroll
  for (int i = 0; i < 4; ++i)
#pragma unroll
    for (int j = 0; j < 4; ++j) acc[i][j] = zero;

  const int KT = K >> 6;

  short8 va[4], vb[4];
#pragma unroll
  for (int i = 0; i < 4; ++i) {
    va[i] = *(const short8*)(A + (size_t)(bm0 + srow[i]) * lda + ssc[i] * 8);
    vb[i] = *(const short8*)(B + (size_t)(bn0 + srow[i]) * ldb + ssc[i] * 8);
  }

  for (int kt = 0; kt < KT; ++kt) {
    __syncthreads();  // previous tile's reads complete
#pragma unroll
    for (int i = 0; i < 4; ++i) {
      // XOR-swizzle: logical chunk c stored at slot c^(row&7)  (bank-conflict-free reads)
      *(short8*)(As + srow[i] * 64 + ((ssc[i] ^ (srow[i] & 7)) * 8)) = va[i];
      *(short8*)(Bs + srow[i] * 64 + ((ssc[i] ^ (srow[i] & 7)) * 8)) = vb[i];
    }
    __syncthreads();
    if (kt + 1 < KT) {  // prefetch next tile into regs; hides under MFMA below
      int k0 = (kt + 1) << 6;
#pragma unroll
      for (int i = 0; i < 4; ++i) {
        va[i] = *(const short8*)(A + (size_t)(bm0 + srow[i]) * lda + k0 + ssc[i] * 8);
        vb[i] = *(const short8*)(B + (size_t)(bn0 + srow[i]) * ldb + k0 + ssc[i] * 8);
      }
    }
#pragma unroll
    for (int c = 0; c < 2; ++c) {
      short8 af[4], bfr[4];
#pragma unroll
      for (int f = 0; f < 4; ++f) {
        int ra = wm * 64 + f * 16 + lc;
        af[f] = *(const short8*)(As + ra * 64 + (((c * 4 + lr) ^ (ra & 7)) * 8));
        int rb = wn * 64 + f * 16 + lc;
        bfr[f] = *(const short8*)(Bs + rb * 64 + (((c * 4 + lr) ^ (rb & 7)) * 8));
      }
#pragma unroll
      for (int mf = 0; mf < 4; ++mf)
#pragma unroll
        for (int nf = 0; nf < 4; ++nf)
          acc[mf][nf] = __builtin_amdgcn_mfma_f32_16x16x32_bf16(af[mf], bfr[nf],
                                                                acc[mf][nf], 0, 0, 0);
    }
  }

  // epilogue: C/D layout col=lane&15, row=(lane>>4)*4+reg
#pragma unroll
  for (int mf = 0; mf < 4; ++mf) {
#pragma unroll
    for (int nf = 0; nf < 4; ++nf) {
      int m0 = bm0 + wm * 64 + mf * 16 + lr * 4;
      int n = bn0 + wn * 64 + nf * 16 + lc;
      f32x4 a = acc[mf][nf];
      if (MODE == 0) {
        int r = r_base + (n >> 10);
        int d = n & 1023;
        float bias = b1v[r * H_SZ + d];
#pragma unroll
        for (int j = 0; j < 4; ++j) {
          float v = fmaxf(a[j] + bias, 0.f) * comb[(size_t)(m0 + j) * 16 + r];
          Hp[(size_t)(m0 + j) * ldh + n] = f2bf(v);
        }
      } else {
#pragma unroll
        for (int j = 0; j < 4; ++j) {
          size_t row = (size_t)(m0 + j);
          float v = a[j];
          if (accum) {
            v += Out[row * H_SZ + n];
          } else {
            float bs = 0.f;
#pragma unroll
            for (int r = 0; r < 16; ++r)
              bs += comb[row * 16 + r] * b2v[r * H_SZ + n];
            v += bs;
          }
          Out[row * H_SZ + n] = v;
        }
      }
    }
  }
}

extern "C" void kernel_launch(void* const* d_in, const int* in_sizes, int n_in,
                              void* d_out, int out_size, void* d_ws, size_t ws_size,
                              hipStream_t stream) {
  if (n_in < 9) return;
  const float* x  = (const float*)d_in[0];
  const float* Wa = (const float*)d_in[1];
  const float* ba = (const float*)d_in[2];
  const float* W1 = (const float*)d_in[3];
  const float* b1 = (const float*)d_in[4];
  const float* W2 = (const float*)d_in[5];
  const float* b2 = (const float*)d_in[6];
  const float* Wc = (const float*)d_in[7];
  const float* bc = (const float*)d_in[8];

  float* out = (float*)d_out;
  float* conf = out + (size_t)B_SZ * H_SZ;

  char* w = (char*)d_ws;
  unsigned short* xb = (unsigned short*)w;  w += (size_t)B_SZ * H_SZ * 2;
  unsigned short* W1T = (unsigned short*)w; w += (size_t)R_SZ * H_SZ * H_SZ * 2;
  unsigned short* W2T = (unsigned short*)w; w += (size_t)R_SZ * H_SZ * H_SZ * 2;
  float* comb = (float*)w;                  w += (size_t)B_SZ * R_SZ * 4;
  float* WaT = (float*)w;                   w += (size_t)R_SZ * H_SZ * 4;
  unsigned short* Hp = (unsigned short*)w;
  size_t used = (size_t)(w - (char*)d_ws);

  // pick largest rule-group size G whose Hp buffer fits in remaining ws
  int G = 16;
  while (G > 1 && used + (size_t)B_SZ * G * H_SZ * 2 > ws_size) G >>= 1;
  if (used + (size_t)B_SZ * G * H_SZ * 2 > ws_size) return;  // ws too small

  dim3 tb(32, 8);
  transpose_cvt<<<dim3(32, 32, 16), tb, 0, stream>>>(W1, W1T, H_SZ, H_SZ);        // per-rule [h,d]->[d,h]
  transpose_cvt<<<dim3(32, 512, 1), tb, 0, stream>>>(W2, W2T, R_SZ * H_SZ, H_SZ); // [(r,d),o]->[o,(r,d)]
  transpose_wa<<<dim3(64), dim3(256), 0, stream>>>(Wa, WaT);
  gate_kernel<<<dim3(B_SZ / 4), dim3(256), 0, stream>>>(x, WaT, ba, Wc, bc, comb, conf, xb);

  int ngroups = R_SZ / G;
  for (int g = 0; g < ngroups; ++g) {
    // Hp[b, (r_local,d)] = comb[b,r] * relu(x @ W1[r] + b1[r])   for r in group g
    gemm_nt<0><<<dim3(G * 8, 64), dim3(256), 0, stream>>>(
        xb, H_SZ,
        W1T + (size_t)g * G * H_SZ * H_SZ, H_SZ, H_SZ,
        Hp, G * H_SZ, b1, nullptr, nullptr, comb, g * G, 0);
    // out[b,o] (+)= Hp @ W2[group rows]  (+ gate-weighted b2 on first group)
    gemm_nt<1><<<dim3(8, 64), dim3(256), 0, stream>>>(
        Hp, G * H_SZ,
        W2T + (size_t)g * G * H_SZ, R_SZ * H_SZ, G * H_SZ,
        nullptr, 0, nullptr, out, b2, comb, 0, (g > 0) ? 1 : 0);
  }
}